// Round 11
// baseline (2201.608 us; speedup 1.0000x reference)
//
#include <hip/hip_runtime.h>
#include <stdint.h>
#include <stddef.h>

typedef unsigned long long u64;
typedef unsigned int u32;
typedef float f32x2 __attribute__((ext_vector_type(2)));

#define NBATCH 8
#define NPTS   8192
#define SG     2048
#define KS     32
#define NGRP   (NBATCH*SG)      // 16384
#define MROWS  (NGRP*KS)        // 524288

// ---- ALL scratch in module-static device globals: immune to ws_size ----
__device__ float4 g_p4[NBATCH*NPTS];          // 1 MiB  {x,y,z,|p|^2}
__device__ float  g_cx[NGRP], g_cy[NGRP], g_cz[NGRP];
__device__ int    g_ball[(size_t)NGRP*KS];    // 2 MiB
__device__ double g_stats[3*128*256];         // 768 KiB
__device__ float  g_A[256], g_Bv[256];        // BN scale/shift: L0 @0, L1 @64, L2 @128
__device__ float  g_mmax[(size_t)NGRP*128];   // 8 MiB
__device__ float  g_mmin[(size_t)NGRP*128];   // 8 MiB
__device__ float  g_y0[(size_t)MROWS*64];     // 134 MiB raw L0 output
__device__ float  g_y1[(size_t)MROWS*64];     // 134 MiB raw L1 output

// ---------------- K_zero ----------------
__global__ __launch_bounds__(256) void k_zero(){
  int idx = blockIdx.x*256 + threadIdx.x;
  if (idx < 3*128*256) g_stats[idx] = 0.0;
}

// ---------------- K_pre ----------------
__global__ __launch_bounds__(256) void k_pre(const float* __restrict__ xyz){
#pragma clang fp contract(off)
  int idx = blockIdx.x*256 + threadIdx.x;
  if (idx >= NBATCH*NPTS) return;
  float x = xyz[idx*3+0];
  float y = xyz[idx*3+1];
  float z = xyz[idx*3+2];
  float xx = x*x; float yy = y*y; float zz = z*z;
  float s2 = (xx + yy) + zz;
  g_p4[idx] = make_float4(x,y,z,s2);
}

// ---------------- K_fps ----------------
// Evidence: r9 (512thr, 8 waves) 1808 -> r10 (fused f64-key max + BCAST
// finisher) 1494us. Still issue-bound: VALUBusy scaled ~78%, 1752cy/iter.
// UPD math is frozen/irreducible; the remaining non-UPD block is the
// stage-2 cross-wave reduce: strided wk8 read + 3 f64-DPP steps (9 VALU
// instr executed by ALL threads) + its dependent chain (ds_read -> 3
// serial DPP -> decode -> pc read).
// r11: replace stage-2 with a ds_max_u64 LDS atomic.
//   * lane63 of each wave (holds the wave max after the 6-DPP in-wave
//     reduce) atomicMax's into a rotating LDS slot kslot[it&3].
//   * after the barrier: ONE broadcast 8B read + decode. No wk8, no
//     strided read, no second DPP stage.
//   * slot rotation: t0 resets slot (it+2)&3 post-barrier. Race-free:
//     reset(it) < barrier(it+1) < atomics(it+2); reads(it-2) <
//     barrier(it-1) < reset(it). All slots zeroed pre-loop (0 is a
//     neutral element: keys > 0 except the impossible all-zero case).
// Exactness: u64-max over the same 8 wave maxes; u64 ordering == f64
// ordering for these keys (positive, NaN-free, unique) — proven r5-r10;
// max associative/commutative => winner bit-identical.
// All else frozen: UPD IEEE sequence (contract off, sub, mul, (a0+a1)+a2,
// fminf), fused key-max, 6-DPP in-wave reduce, epilogue-only global
// stores, fars LDS.

#define NT  512
#define PPT 16

#define FOR8(M) M(0) M(1) M(2) M(3) M(4) M(5) M(6) M(7)

#define DECLP2(i) f32x2 px##i, py##i, pz##i, dd##i;

#define LOADP2(i) { float4 pA = g_p4[base + (2*(i)  )*NT + t]; \
                    float4 pB = g_p4[base + (2*(i)+1)*NT + t]; \
                    px##i.x = pA.x; px##i.y = pB.x; \
                    py##i.x = pA.y; py##i.y = pB.y; \
                    pz##i.x = pA.z; pz##i.y = pB.z; \
                    dd##i.x = 1e10f; dd##i.y = 1e10f; }

// element-wise identical math: sub, square, (a0+a1)+a2, fminf;
// then fuse the argmax via f64-bit key max (klo hoisted, loop-invariant)
#define UPD2(i) { f32x2 dx = px##i - fcx; \
                  f32x2 dy = py##i - fcy; \
                  f32x2 dz = pz##i - fcz; \
                  f32x2 a0 = dx*dx; f32x2 a1 = dy*dy; f32x2 a2 = dz*dz; \
                  f32x2 d  = (a0 + a1) + a2; \
                  float ndx = fminf(dd##i.x, d.x); \
                  float ndy = fminf(dd##i.y, d.y); \
                  dd##i.x = ndx; dd##i.y = ndy; \
                  u64 kx = ((u64)__float_as_uint(ndx) << 32) | klo[2*(i)]; \
                  u64 ky = ((u64)__float_as_uint(ndy) << 32) | klo[2*(i)+1]; \
                  kk = fmax(kk, __longlong_as_double((long long)kx)); \
                  kk = fmax(kk, __longlong_as_double((long long)ky)); }

// one DPP max step on an f64-bits key: 2 dpp movs + v_max_f64
template <int CTRL>
__device__ __forceinline__ double dpp_max_step(double v){
  u64 k  = (u64)__double_as_longlong(v);
  int lo = __builtin_amdgcn_update_dpp(0, (int)(u32)k,        CTRL, 0xf, 0xf, true);
  int hi = __builtin_amdgcn_update_dpp(0, (int)(u32)(k>>32),  CTRL, 0xf, 0xf, true);
  double nv = __longlong_as_double((long long)(((u64)(u32)hi << 32) | (u32)lo));
  return fmax(v, nv);
}

__global__ __launch_bounds__(NT, 1) void k_fps(const int* __restrict__ start, float* __restrict__ out_xyz){
  const int b = blockIdx.x;
  const int t = threadIdx.x;
  const int base = b*NPTS;
  __shared__ u64   kslot[4];                   // rotating atomic-max slots
  __shared__ int    fars[SG];                  // 8 KiB winning indices
  __shared__ __align__(16) float4 pc[NPTS];    // 128 KiB point cache

  // one-time preload of this batch's points into LDS
  for (int i = t; i < NPTS; i += NT) pc[i] = g_p4[base + i];
  if (t < 4) kslot[t] = 0ull;

  FOR8(DECLP2)
  FOR8(LOADP2)

  // loop-invariant key low-words: klo[j] = 8191 - (j*NT + t)
  u32 klo[PPT];
#pragma unroll
  for (int j = 0; j < PPT; ++j) klo[j] = (u32)(NPTS-1 - (j*NT + t));

  int far = start[b];
  __syncthreads();                             // pc + kslot ready
  float4 fc = pc[far];
  if (t==0) fars[0] = far;
  const int lane = t & 63;
  for (int it=1; it<SG; ++it){
    double kk = 0.0;                           // exact: all keys >= +0.0
    {
#pragma clang fp contract(off)
      const f32x2 fcx = {fc.x, fc.x};
      const f32x2 fcy = {fc.y, fc.y};
      const f32x2 fcz = {fc.z, fc.z};
      FOR8(UPD2)
    }
    // in-wave 64 -> lane63 (row reduce + bcast finisher, all-VALU)
    double kv = kk;
    kv = dpp_max_step<0xB1>(kv);    // quad_perm [1,0,3,2]  (xor1)
    kv = dpp_max_step<0x4E>(kv);    // quad_perm [2,3,0,1]  (xor2)
    kv = dpp_max_step<0x141>(kv);   // ROW_HALF_MIRROR      (8-group)
    kv = dpp_max_step<0x140>(kv);   // ROW_MIRROR           (16-group)
    kv = dpp_max_step<0x142>(kv);   // ROW_BCAST15: row r -> row r+1
    kv = dpp_max_step<0x143>(kv);   // ROW_BCAST31: half 0 -> half 1
    if (lane == 63)
      atomicMax(&kslot[it & 3], (u64)__double_as_longlong(kv));
    __syncthreads();
    u64 kmu = kslot[it & 3];                   // broadcast 8B read
    far = NPTS-1 - (int)(kmu & 0xffffffffu);
    fc = pc[far];
    if (t==0){
      fars[it] = far;                          // LDS only — no vmem in loop
      kslot[(it+2) & 3] = 0ull;                // reset for iter it+2
    }
  }
  __syncthreads();                             // fars complete
  // epilogue: write all centroids once (same values, same locations)
  for (int it = t; it < SG; it += NT){
    int f = fars[it];
    float4 p = pc[f];
    int gidx = b*SG + it;
    g_cx[gidx] = p.x; g_cy[gidx] = p.y; g_cz[gidx] = p.z;
    size_t o = (size_t)gidx*3;
    out_xyz[o+0]=p.x; out_xyz[o+1]=p.y; out_xyz[o+2]=p.z;
  }
}

// ---------------- K_ball: expansion form, FMA-ascending dot (PASSED r7, do not touch) ----------------
__global__ __launch_bounds__(256) void k_ball(){
  const int g = blockIdx.x*4 + (threadIdx.x>>6);
  const int lane = threadIdx.x & 63;
  const int b = g >> 11;
  const float4* pb4 = g_p4 + b*NPTS;
  float cxv = g_cx[g], cyv = g_cy[g], czv = g_cz[g];
  float s1;
  {
#pragma clang fp contract(off)
    float a = cxv*cxv; float bb = cyv*cyv; float cc = czv*czv;
    s1 = (a + bb) + cc;
  }
  const float R2 = 0.04f;
  int filled = 0, firstn = -1;
  for (int n0=0; n0<NPTS && filled<KS; n0+=64){
    float4 p = pb4[n0+lane];
    float sq;
    {
#pragma clang fp contract(off)
      float dt = cxv*p.x;
      dt = fmaf(cyv, p.y, dt);
      dt = fmaf(czv, p.z, dt);
      float ss = s1 + p.w;
      sq = ss - 2.0f*dt;
    }
    bool mem = !(sq > R2);
    u64 mk = __ballot(mem);
    if (firstn < 0 && mk) firstn = n0 + (__ffsll((unsigned long long)mk) - 1);
    int pos = filled + (int)__popcll(mk & ((1ull<<lane)-1ull));
    if (mem && pos < KS) g_ball[(size_t)g*KS + pos] = n0 + lane;
    filled += (int)__popcll(mk);
  }
  for (int s = filled + lane; s < KS; s += 64) g_ball[(size_t)g*KS+s] = firstn;
}

// ---------------- K_mlpA: gather + L0 -> Y0 (raw f32) + stats0 ----------------
__global__ __launch_bounds__(256) void k_mlpA(
    const float* __restrict__ points,
    const float* __restrict__ W0, const float* __restrict__ B0v){
  double* stats = g_stats;
  const int g = blockIdx.x, tid = threadIdx.x;
  const int b = g >> 11;
  __shared__ __align__(16) float xt[32][68];
  __shared__ __align__(16) float w0s[68][64];
  __shared__ float wsum[4][64], wsq[4][64];

  for (int i = tid; i < 67*64; i += 256) w0s[i>>6][i&63] = W0[i];
  if (tid < 64) w0s[67][tid] = 0.f;

  if (tid < 32){
    int n = g_ball[(size_t)g*KS + tid];
    float4 p = g_p4[b*NPTS + n];
    xt[tid][0] = p.x - g_cx[g];
    xt[tid][1] = p.y - g_cy[g];
    xt[tid][2] = p.z - g_cz[g];
    xt[tid][67] = 0.f;
  }
  {
    int k = tid >> 3, j = tid & 7;
    int n = g_ball[(size_t)g*KS + k];
    const float4* pr = (const float4*)(points + ((size_t)(b*NPTS + n))*64);
    float4 v0 = pr[j*2], v1 = pr[j*2+1];
    int c0 = 3 + j*8;
    xt[k][c0+0]=v0.x; xt[k][c0+1]=v0.y; xt[k][c0+2]=v0.z; xt[k][c0+3]=v0.w;
    xt[k][c0+4]=v1.x; xt[k][c0+5]=v1.y; xt[k][c0+6]=v1.z; xt[k][c0+7]=v1.w;
  }
  __syncthreads();

  const int k0 = (tid >> 4) * 2;
  const int d0 = (tid & 15) * 4;
  const int lane = tid & 63, w = tid >> 6;

  float acc0[4] = {0.f,0.f,0.f,0.f};
  float acc1[4] = {0.f,0.f,0.f,0.f};
#pragma unroll
  for (int cq = 0; cq < 17; ++cq){
    const int c = cq*4;
    float xa[4], xb[4], r0[4], r1[4], r2[4], r3[4];
    *(float4*)xa = *(const float4*)&xt[k0][c];
    *(float4*)xb = *(const float4*)&xt[k0+1][c];
    *(float4*)r0 = *(const float4*)&w0s[c+0][d0];
    *(float4*)r1 = *(const float4*)&w0s[c+1][d0];
    *(float4*)r2 = *(const float4*)&w0s[c+2][d0];
    *(float4*)r3 = *(const float4*)&w0s[c+3][d0];
#pragma unroll
    for (int j=0;j<4;j++){
      acc0[j] = fmaf(xa[0], r0[j], acc0[j]);
      acc0[j] = fmaf(xa[1], r1[j], acc0[j]);
      acc0[j] = fmaf(xa[2], r2[j], acc0[j]);
      acc0[j] = fmaf(xa[3], r3[j], acc0[j]);
      acc1[j] = fmaf(xb[0], r0[j], acc1[j]);
      acc1[j] = fmaf(xb[1], r1[j], acc1[j]);
      acc1[j] = fmaf(xb[2], r2[j], acc1[j]);
      acc1[j] = fmaf(xb[3], r3[j], acc1[j]);
    }
  }
#pragma unroll
  for (int j=0;j<4;j++){ float bv = B0v[d0+j]; acc0[j] += bv; acc1[j] += bv; }

  // store raw Y0
  {
    size_t r0 = ((size_t)g*KS + k0)*64 + d0;
    *(float4*)&g_y0[r0]      = *(float4*)acc0;
    *(float4*)&g_y0[r0 + 64] = *(float4*)acc1;
  }

  float s[4], q[4];
#pragma unroll
  for (int j=0;j<4;j++){ s[j] = acc0[j]+acc1[j]; q[j] = acc0[j]*acc0[j] + acc1[j]*acc1[j]; }
#pragma unroll
  for (int j=0;j<4;j++){
    s[j] += __shfl_down(s[j],32); s[j] += __shfl_down(s[j],16);
    q[j] += __shfl_down(q[j],32); q[j] += __shfl_down(q[j],16);
  }
  if (lane < 16){
#pragma unroll
    for (int j=0;j<4;j++){ wsum[w][lane*4+j] = s[j]; wsq[w][lane*4+j] = q[j]; }
  }
  __syncthreads();
  if (tid < 64){
    float S = wsum[0][tid]+wsum[1][tid]+wsum[2][tid]+wsum[3][tid];
    float Q = wsq[0][tid]+wsq[1][tid]+wsq[2][tid]+wsq[3][tid];
    int bucket = g & 127;
    atomicAdd(&stats[(size_t)bucket*256 + tid], (double)S);
    atomicAdd(&stats[(size_t)bucket*256 + 128 + tid], (double)Q);
  }
}

// ---------------- K_mlpB: Y0 + BN0/ReLU -> L1 -> Y1 (raw) + stats1 ----------------
__global__ __launch_bounds__(256) void k_mlpB(
    const float* __restrict__ W1, const float* __restrict__ B1v){
  double* stats = g_stats + (size_t)1*128*256;
  const int g = blockIdx.x, tid = threadIdx.x;
  __shared__ __align__(16) float xn[32][68];
  __shared__ __align__(16) float w1s[64][64];
  __shared__ float wsum[4][64], wsq[4][64];

  for (int i = tid; i < 64*64; i += 256) w1s[i>>6][i&63] = W1[i];
  {
    int k = tid >> 3, j = tid & 7;
    const float4* pr = (const float4*)(g_y0 + ((size_t)g*KS + k)*64);
    float4 v0 = pr[j*2], v1 = pr[j*2+1];
    int c0 = j*8;
    xn[k][c0+0] = fmaxf(fmaf(v0.x, g_A[c0+0], g_Bv[c0+0]), 0.f);
    xn[k][c0+1] = fmaxf(fmaf(v0.y, g_A[c0+1], g_Bv[c0+1]), 0.f);
    xn[k][c0+2] = fmaxf(fmaf(v0.z, g_A[c0+2], g_Bv[c0+2]), 0.f);
    xn[k][c0+3] = fmaxf(fmaf(v0.w, g_A[c0+3], g_Bv[c0+3]), 0.f);
    xn[k][c0+4] = fmaxf(fmaf(v1.x, g_A[c0+4], g_Bv[c0+4]), 0.f);
    xn[k][c0+5] = fmaxf(fmaf(v1.y, g_A[c0+5], g_Bv[c0+5]), 0.f);
    xn[k][c0+6] = fmaxf(fmaf(v1.z, g_A[c0+6], g_Bv[c0+6]), 0.f);
    xn[k][c0+7] = fmaxf(fmaf(v1.w, g_A[c0+7], g_Bv[c0+7]), 0.f);
  }
  __syncthreads();

  const int k0 = (tid >> 4) * 2;
  const int d0 = (tid & 15) * 4;
  const int lane = tid & 63, w = tid >> 6;

  float bc0[4] = {0.f,0.f,0.f,0.f};
  float bc1[4] = {0.f,0.f,0.f,0.f};
#pragma unroll
  for (int cq = 0; cq < 16; ++cq){
    const int c = cq*4;
    float xa[4], xb[4], r0[4], r1[4], r2[4], r3[4];
    *(float4*)xa = *(const float4*)&xn[k0][c];
    *(float4*)xb = *(const float4*)&xn[k0+1][c];
    *(float4*)r0 = *(const float4*)&w1s[c+0][d0];
    *(float4*)r1 = *(const float4*)&w1s[c+1][d0];
    *(float4*)r2 = *(const float4*)&w1s[c+2][d0];
    *(float4*)r3 = *(const float4*)&w1s[c+3][d0];
#pragma unroll
    for (int j=0;j<4;j++){
      bc0[j] = fmaf(xa[0], r0[j], bc0[j]);
      bc0[j] = fmaf(xa[1], r1[j], bc0[j]);
      bc0[j] = fmaf(xa[2], r2[j], bc0[j]);
      bc0[j] = fmaf(xa[3], r3[j], bc0[j]);
      bc1[j] = fmaf(xb[0], r0[j], bc1[j]);
      bc1[j] = fmaf(xb[1], r1[j], bc1[j]);
      bc1[j] = fmaf(xb[2], r2[j], bc1[j]);
      bc1[j] = fmaf(xb[3], r3[j], bc1[j]);
    }
  }
#pragma unroll
  for (int j=0;j<4;j++){ float bv = B1v[d0+j]; bc0[j] += bv; bc1[j] += bv; }

  {
    size_t r0 = ((size_t)g*KS + k0)*64 + d0;
    *(float4*)&g_y1[r0]      = *(float4*)bc0;
    *(float4*)&g_y1[r0 + 64] = *(float4*)bc1;
  }

  float s[4], q[4];
#pragma unroll
  for (int j=0;j<4;j++){ s[j] = bc0[j]+bc1[j]; q[j] = bc0[j]*bc0[j] + bc1[j]*bc1[j]; }
#pragma unroll
  for (int j=0;j<4;j++){
    s[j] += __shfl_down(s[j],32); s[j] += __shfl_down(s[j],16);
    q[j] += __shfl_down(q[j],32); q[j] += __shfl_down(q[j],16);
  }
  if (lane < 16){
#pragma unroll
    for (int j=0;j<4;j++){ wsum[w][lane*4+j] = s[j]; wsq[w][lane*4+j] = q[j]; }
  }
  __syncthreads();
  if (tid < 64){
    float S = wsum[0][tid]+wsum[1][tid]+wsum[2][tid]+wsum[3][tid];
    float Q = wsq[0][tid]+wsq[1][tid]+wsq[2][tid]+wsq[3][tid];
    int bucket = g & 127;
    atomicAdd(&stats[(size_t)bucket*256 + tid], (double)S);
    atomicAdd(&stats[(size_t)bucket*256 + 128 + tid], (double)Q);
  }
}

// ---------------- K_mlpC: Y1 + BN1/ReLU -> L2 -> stats2 + max/min ----------------
__global__ __launch_bounds__(256) void k_mlpC(
    const float* __restrict__ W2, const float* __restrict__ B2v){
  double* stats = g_stats + (size_t)2*128*256;
  const int g = blockIdx.x, tid = threadIdx.x;
  __shared__ __align__(16) float xt[32][68];
  __shared__ __align__(16) float w2s[64][128];
  __shared__ float wsum[4][128], wsq[4][128];
  __shared__ float wmx[4][128], wmn[4][128];

  for (int i = tid; i < 64*128; i += 256) w2s[i>>7][i&127] = W2[i];
  {
    int k = tid >> 3, j = tid & 7;
    const float4* pr = (const float4*)(g_y1 + ((size_t)g*KS + k)*64);
    float4 v0 = pr[j*2], v1 = pr[j*2+1];
    int c0 = j*8;
    xt[k][c0+0] = fmaxf(fmaf(v0.x, g_A[64+c0+0], g_Bv[64+c0+0]), 0.f);
    xt[k][c0+1] = fmaxf(fmaf(v0.y, g_A[64+c0+1], g_Bv[64+c0+1]), 0.f);
    xt[k][c0+2] = fmaxf(fmaf(v0.z, g_A[64+c0+2], g_Bv[64+c0+2]), 0.f);
    xt[k][c0+3] = fmaxf(fmaf(v0.w, g_A[64+c0+3], g_Bv[64+c0+3]), 0.f);
    xt[k][c0+4] = fmaxf(fmaf(v1.x, g_A[64+c0+4], g_Bv[64+c0+4]), 0.f);
    xt[k][c0+5] = fmaxf(fmaf(v1.y, g_A[64+c0+5], g_Bv[64+c0+5]), 0.f);
    xt[k][c0+6] = fmaxf(fmaf(v1.z, g_A[64+c0+6], g_Bv[64+c0+6]), 0.f);
    xt[k][c0+7] = fmaxf(fmaf(v1.w, g_A[64+c0+7], g_Bv[64+c0+7]), 0.f);
  }
  __syncthreads();

  const int k0 = (tid >> 4) * 2;
  const int e0 = (tid & 15) * 8;
  const int lane = tid & 63, w = tid >> 6;

  float c0a[8] = {0.f,0.f,0.f,0.f,0.f,0.f,0.f,0.f};
  float c1a[8] = {0.f,0.f,0.f,0.f,0.f,0.f,0.f,0.f};
#pragma unroll
  for (int cq = 0; cq < 16; ++cq){
    const int c = cq*4;
    float xa[4], xb[4], r0[8], r1[8], r2[8], r3[8];
    *(float4*)xa = *(const float4*)&xt[k0][c];
    *(float4*)xb = *(const float4*)&xt[k0+1][c];
    *(float4*)&r0[0] = *(const float4*)&w2s[c+0][e0]; *(float4*)&r0[4] = *(const float4*)&w2s[c+0][e0+4];
    *(float4*)&r1[0] = *(const float4*)&w2s[c+1][e0]; *(float4*)&r1[4] = *(const float4*)&w2s[c+1][e0+4];
    *(float4*)&r2[0] = *(const float4*)&w2s[c+2][e0]; *(float4*)&r2[4] = *(const float4*)&w2s[c+2][e0+4];
    *(float4*)&r3[0] = *(const float4*)&w2s[c+3][e0]; *(float4*)&r3[4] = *(const float4*)&w2s[c+3][e0+4];
#pragma unroll
    for (int j=0;j<8;j++){
      c0a[j] = fmaf(xa[0], r0[j], c0a[j]);
      c0a[j] = fmaf(xa[1], r1[j], c0a[j]);
      c0a[j] = fmaf(xa[2], r2[j], c0a[j]);
      c0a[j] = fmaf(xa[3], r3[j], c0a[j]);
      c1a[j] = fmaf(xb[0], r0[j], c1a[j]);
      c1a[j] = fmaf(xb[1], r1[j], c1a[j]);
      c1a[j] = fmaf(xb[2], r2[j], c1a[j]);
      c1a[j] = fmaf(xb[3], r3[j], c1a[j]);
    }
  }
#pragma unroll
  for (int j=0;j<8;j++){ float bv = B2v[e0+j]; c0a[j] += bv; c1a[j] += bv; }

  float s[8], q[8], mx[8], mn[8];
#pragma unroll
  for (int j=0;j<8;j++){
    s[j] = c0a[j]+c1a[j]; q[j] = c0a[j]*c0a[j] + c1a[j]*c1a[j];
    mx[j] = fmaxf(c0a[j], c1a[j]); mn[j] = fminf(c0a[j], c1a[j]);
  }
#pragma unroll
  for (int j=0;j<8;j++){
    s[j] += __shfl_down(s[j],32); s[j] += __shfl_down(s[j],16);
    q[j] += __shfl_down(q[j],32); q[j] += __shfl_down(q[j],16);
    mx[j] = fmaxf(mx[j], __shfl_xor(mx[j],16)); mx[j] = fmaxf(mx[j], __shfl_xor(mx[j],32));
    mn[j] = fminf(mn[j], __shfl_xor(mn[j],16)); mn[j] = fminf(mn[j], __shfl_xor(mn[j],32));
  }
  if (lane < 16){
#pragma unroll
    for (int j=0;j<8;j++){
      wsum[w][lane*8+j] = s[j]; wsq[w][lane*8+j] = q[j];
      wmx[w][lane*8+j] = mx[j]; wmn[w][lane*8+j] = mn[j];
    }
  }
  __syncthreads();
  if (tid < 128){
    float S = wsum[0][tid]+wsum[1][tid]+wsum[2][tid]+wsum[3][tid];
    float Q = wsq[0][tid]+wsq[1][tid]+wsq[2][tid]+wsq[3][tid];
    float MX = fmaxf(fmaxf(wmx[0][tid],wmx[1][tid]), fmaxf(wmx[2][tid],wmx[3][tid]));
    float MN = fminf(fminf(wmn[0][tid],wmn[1][tid]), fminf(wmn[2][tid],wmn[3][tid]));
    g_mmax[(size_t)g*128 + tid] = MX;
    g_mmin[(size_t)g*128 + tid] = MN;
    int bucket = g & 127;
    atomicAdd(&stats[(size_t)bucket*256 + tid], (double)S);
    atomicAdd(&stats[(size_t)bucket*256 + 128 + tid], (double)Q);
  }
}

// ---------------- K_stats ----------------
__global__ void k_stats(int stage, const float* __restrict__ gamma,
                        const float* __restrict__ beta, int aoff, int cout){
  int c = threadIdx.x;
  if (c >= cout) return;
  const double* stats = g_stats + (size_t)stage*128*256;
  double S=0.0, Q=0.0;
  for (int k=0;k<128;k++){ S += stats[(size_t)k*256 + c]; Q += stats[(size_t)k*256 + 128 + c]; }
  const double M = (double)MROWS;
  double mean = S / M;
  double var  = Q / M - mean*mean;
  double inv  = 1.0 / sqrt(var + 1e-5);
  double a    = (double)gamma[c] * inv;
  g_A[aoff+c]  = (float)a;
  g_Bv[aoff+c] = (float)((double)beta[c] - mean * a);
}

// ---------------- K_final ----------------
__global__ __launch_bounds__(256) void k_final(float* __restrict__ outp){
  int idx = blockIdx.x*256 + threadIdx.x;
  int d = idx & 127;
  float a = g_A[128+d], b = g_Bv[128+d];
  float y = (a >= 0.f) ? g_mmax[idx] : g_mmin[idx];
  float v = fmaf(y, a, b);
  outp[idx] = fmaxf(v, 0.f);
}

extern "C" void kernel_launch(void* const* d_in, const int* in_sizes, int n_in,
                              void* d_out, int out_size, void* d_ws, size_t ws_size,
                              hipStream_t stream) {
  (void)in_sizes; (void)n_in; (void)out_size; (void)d_ws; (void)ws_size;
  const float* xyz    = (const float*)d_in[0];
  const float* points = (const float*)d_in[1];
  const int*   start  = (const int*)d_in[2];
  const float* W0 = (const float*)d_in[3];  const float* b0 = (const float*)d_in[4];
  const float* g0 = (const float*)d_in[5];  const float* be0= (const float*)d_in[6];
  const float* W1 = (const float*)d_in[7];  const float* b1 = (const float*)d_in[8];
  const float* g1 = (const float*)d_in[9];  const float* be1= (const float*)d_in[10];
  const float* W2 = (const float*)d_in[11]; const float* b2 = (const float*)d_in[12];
  const float* g2 = (const float*)d_in[13]; const float* be2= (const float*)d_in[14];

  float* out_xyz = (float*)d_out;
  float* out_pts = (float*)d_out + (size_t)NBATCH*SG*3;

  k_zero <<<384, 256, 0, stream>>>();
  k_pre  <<<256, 256, 0, stream>>>(xyz);
  k_fps  <<<NBATCH, NT, 0, stream>>>(start, out_xyz);
  k_ball <<<4096, 256, 0, stream>>>();

  k_mlpA<<<NGRP, 256, 0, stream>>>(points, W0, b0);
  k_stats<<<1, 128, 0, stream>>>(0, g0, be0, 0, 64);
  k_mlpB<<<NGRP, 256, 0, stream>>>(W1, b1);
  k_stats<<<1, 128, 0, stream>>>(1, g1, be1, 64, 64);
  k_mlpC<<<NGRP, 256, 0, stream>>>(W2, b2);
  k_stats<<<1, 128, 0, stream>>>(2, g2, be2, 128, 128);
  k_final<<<8192, 256, 0, stream>>>(out_pts);
}

// Round 12
// 2091.262 us; speedup vs baseline: 1.0528x; 1.0528x over previous
//
#include <hip/hip_runtime.h>
#include <stdint.h>
#include <stddef.h>

typedef unsigned long long u64;
typedef unsigned int u32;
typedef float f32x2 __attribute__((ext_vector_type(2)));

#define NBATCH 8
#define NPTS   8192
#define SG     2048
#define KS     32
#define NGRP   (NBATCH*SG)      // 16384
#define MROWS  (NGRP*KS)        // 524288

// ---- ALL scratch in module-static device globals: immune to ws_size ----
__device__ float4 g_p4[NBATCH*NPTS];          // 1 MiB  {x,y,z,|p|^2}
__device__ float  g_cx[NGRP], g_cy[NGRP], g_cz[NGRP];
__device__ int    g_ball[(size_t)NGRP*KS];    // 2 MiB
__device__ double g_stats[3*128*256];         // 768 KiB
__device__ float  g_A[256], g_Bv[256];        // BN scale/shift: L0 @0, L1 @64, L2 @128
__device__ float  g_mmax[(size_t)NGRP*128];   // 8 MiB
__device__ float  g_mmin[(size_t)NGRP*128];   // 8 MiB
__device__ float  g_y0[(size_t)MROWS*64];     // 134 MiB raw L0 output
__device__ float  g_y1[(size_t)MROWS*64];     // 134 MiB raw L1 output

// ---------------- K_zero ----------------
__global__ __launch_bounds__(256) void k_zero(){
  int idx = blockIdx.x*256 + threadIdx.x;
  if (idx < 3*128*256) g_stats[idx] = 0.0;
}

// ---------------- K_pre ----------------
__global__ __launch_bounds__(256) void k_pre(const float* __restrict__ xyz){
#pragma clang fp contract(off)
  int idx = blockIdx.x*256 + threadIdx.x;
  if (idx >= NBATCH*NPTS) return;
  float x = xyz[idx*3+0];
  float y = xyz[idx*3+1];
  float z = xyz[idx*3+2];
  float xx = x*x; float yy = y*y; float zz = z*z;
  float s2 = (xx + yy) + zz;
  g_p4[idx] = make_float4(x,y,z,s2);
}

// ---------------- K_fps ----------------
// FINAL (r12 = revert to r10, the session's verified best: 1494us).
// Campaign ledger: 2573 (r0 baseline) -> 1494us (-42%):
//   r5: LDS point cache (fc from pc[], no global loads in loop)
//   r6: DPP in-wave reduce (f64-bit key max, all-VALU)
//   r7: epilogue-only global stores (no vmem in loop)
//   r8: packed-f32 (VOP3P) distance math
//   r9: 512thr x 16ppt — 8 waves/barrier (barrier-population was the
//       hidden ~1000cy/iter term; -17%)
//   r10: fused f64-key max in UPD (deletes scan/tie-break chain; -17%)
//   r11: LDS atomicMax stage-2 — REGRESSED +8% (same-address u64 DS
//       atomics serialize ~8x60cy > the ~200cy DPP stage it replaced);
//       reverted. Lesson: at fan-in 8, redundant DPP beats atomics.
// Status: issue-bound at ~78% VALUBusy (scaled) on exactness-frozen UPD
// math; reduce path has 3 nulls + 1 regression; 4-wave variant blocked by
// the ~88-VGPR allocation. Structural floor for this decomposition.
// Exactness: UPD IEEE sequence frozen (contract off, sub, mul,
// (a0+a1)+a2, fminf); klo[j]=8191-(j*NT+t) key low-words; f64-bit key
// ordering == u64 ordering (keys positive, NaN-free, unique); max
// associative => winner and centroid sequence bit-identical to the
// original passing version. wk8 dbuf race-free (reads of iter it precede
// writes of it+2 via two barriers).

#define NT  512
#define PPT 16

#define FOR8(M) M(0) M(1) M(2) M(3) M(4) M(5) M(6) M(7)

#define DECLP2(i) f32x2 px##i, py##i, pz##i, dd##i;

#define LOADP2(i) { float4 pA = g_p4[base + (2*(i)  )*NT + t]; \
                    float4 pB = g_p4[base + (2*(i)+1)*NT + t]; \
                    px##i.x = pA.x; px##i.y = pB.x; \
                    py##i.x = pA.y; py##i.y = pB.y; \
                    pz##i.x = pA.z; pz##i.y = pB.z; \
                    dd##i.x = 1e10f; dd##i.y = 1e10f; }

// element-wise identical math: sub, square, (a0+a1)+a2, fminf;
// then fuse the argmax via f64-bit key max (klo hoisted, loop-invariant)
#define UPD2(i) { f32x2 dx = px##i - fcx; \
                  f32x2 dy = py##i - fcy; \
                  f32x2 dz = pz##i - fcz; \
                  f32x2 a0 = dx*dx; f32x2 a1 = dy*dy; f32x2 a2 = dz*dz; \
                  f32x2 d  = (a0 + a1) + a2; \
                  float ndx = fminf(dd##i.x, d.x); \
                  float ndy = fminf(dd##i.y, d.y); \
                  dd##i.x = ndx; dd##i.y = ndy; \
                  u64 kx = ((u64)__float_as_uint(ndx) << 32) | klo[2*(i)]; \
                  u64 ky = ((u64)__float_as_uint(ndy) << 32) | klo[2*(i)+1]; \
                  kk = fmax(kk, __longlong_as_double((long long)kx)); \
                  kk = fmax(kk, __longlong_as_double((long long)ky)); }

// one DPP max step on an f64-bits key: 2 dpp movs + v_max_f64
template <int CTRL>
__device__ __forceinline__ double dpp_max_step(double v){
  u64 k  = (u64)__double_as_longlong(v);
  int lo = __builtin_amdgcn_update_dpp(0, (int)(u32)k,        CTRL, 0xf, 0xf, true);
  int hi = __builtin_amdgcn_update_dpp(0, (int)(u32)(k>>32),  CTRL, 0xf, 0xf, true);
  double nv = __longlong_as_double((long long)(((u64)(u32)hi << 32) | (u32)lo));
  return fmax(v, nv);
}

__global__ __launch_bounds__(NT, 1) void k_fps(const int* __restrict__ start, float* __restrict__ out_xyz){
  const int b = blockIdx.x;
  const int t = threadIdx.x;
  const int base = b*NPTS;
  __shared__ double wk8[2][8];                 // per-wave partials, dbuf
  __shared__ int    fars[SG];                  // 8 KiB winning indices
  __shared__ __align__(16) float4 pc[NPTS];    // 128 KiB point cache

  // one-time preload of this batch's points into LDS
  for (int i = t; i < NPTS; i += NT) pc[i] = g_p4[base + i];

  FOR8(DECLP2)
  FOR8(LOADP2)

  // loop-invariant key low-words: klo[j] = 8191 - (j*NT + t)
  u32 klo[PPT];
#pragma unroll
  for (int j = 0; j < PPT; ++j) klo[j] = (u32)(NPTS-1 - (j*NT + t));

  int far = start[b];
  __syncthreads();                             // pc ready
  float4 fc = pc[far];
  if (t==0) fars[0] = far;
  const int lane = t & 63, w = t >> 6;   // w in 0..7
  for (int it=1; it<SG; ++it){
    double kk = 0.0;                           // exact: all keys >= +0.0
    {
#pragma clang fp contract(off)
      const f32x2 fcx = {fc.x, fc.x};
      const f32x2 fcy = {fc.y, fc.y};
      const f32x2 fcz = {fc.z, fc.z};
      FOR8(UPD2)
    }
    // in-wave 64 -> lane63 (row reduce + bcast finisher, all-VALU)
    double kv = kk;
    kv = dpp_max_step<0xB1>(kv);    // quad_perm [1,0,3,2]  (xor1)
    kv = dpp_max_step<0x4E>(kv);    // quad_perm [2,3,0,1]  (xor2)
    kv = dpp_max_step<0x141>(kv);   // ROW_HALF_MIRROR      (8-group)
    kv = dpp_max_step<0x140>(kv);   // ROW_MIRROR           (16-group)
    kv = dpp_max_step<0x142>(kv);   // ROW_BCAST15: row r -> row r+1
    kv = dpp_max_step<0x143>(kv);   // ROW_BCAST31: half 0 -> half 1
    const int s = it & 1;
    if (lane == 63) wk8[s][w] = kv; // lane 63 holds the wave max
    __syncthreads();
    // every lane: read one of the 8 partials (broadcast reads), then
    // 3 DPP steps reduce each 8-lane group -> global max in every lane
    double km = wk8[s][lane & 7];
    km = dpp_max_step<0xB1>(km);
    km = dpp_max_step<0x4E>(km);
    km = dpp_max_step<0x141>(km);
    u64 kmu = (u64)__double_as_longlong(km);
    far = NPTS-1 - (int)(kmu & 0xffffffffu);
    fc = pc[far];
    if (t==0) fars[it] = far;                  // LDS only — no vmem in loop
  }
  __syncthreads();                             // fars complete
  // epilogue: write all centroids once (same values, same locations)
  for (int it = t; it < SG; it += NT){
    int f = fars[it];
    float4 p = pc[f];
    int gidx = b*SG + it;
    g_cx[gidx] = p.x; g_cy[gidx] = p.y; g_cz[gidx] = p.z;
    size_t o = (size_t)gidx*3;
    out_xyz[o+0]=p.x; out_xyz[o+1]=p.y; out_xyz[o+2]=p.z;
  }
}

// ---------------- K_ball: expansion form, FMA-ascending dot (PASSED r7, do not touch) ----------------
__global__ __launch_bounds__(256) void k_ball(){
  const int g = blockIdx.x*4 + (threadIdx.x>>6);
  const int lane = threadIdx.x & 63;
  const int b = g >> 11;
  const float4* pb4 = g_p4 + b*NPTS;
  float cxv = g_cx[g], cyv = g_cy[g], czv = g_cz[g];
  float s1;
  {
#pragma clang fp contract(off)
    float a = cxv*cxv; float bb = cyv*cyv; float cc = czv*czv;
    s1 = (a + bb) + cc;
  }
  const float R2 = 0.04f;
  int filled = 0, firstn = -1;
  for (int n0=0; n0<NPTS && filled<KS; n0+=64){
    float4 p = pb4[n0+lane];
    float sq;
    {
#pragma clang fp contract(off)
      float dt = cxv*p.x;
      dt = fmaf(cyv, p.y, dt);
      dt = fmaf(czv, p.z, dt);
      float ss = s1 + p.w;
      sq = ss - 2.0f*dt;
    }
    bool mem = !(sq > R2);
    u64 mk = __ballot(mem);
    if (firstn < 0 && mk) firstn = n0 + (__ffsll((unsigned long long)mk) - 1);
    int pos = filled + (int)__popcll(mk & ((1ull<<lane)-1ull));
    if (mem && pos < KS) g_ball[(size_t)g*KS + pos] = n0 + lane;
    filled += (int)__popcll(mk);
  }
  for (int s = filled + lane; s < KS; s += 64) g_ball[(size_t)g*KS+s] = firstn;
}

// ---------------- K_mlpA: gather + L0 -> Y0 (raw f32) + stats0 ----------------
__global__ __launch_bounds__(256) void k_mlpA(
    const float* __restrict__ points,
    const float* __restrict__ W0, const float* __restrict__ B0v){
  double* stats = g_stats;
  const int g = blockIdx.x, tid = threadIdx.x;
  const int b = g >> 11;
  __shared__ __align__(16) float xt[32][68];
  __shared__ __align__(16) float w0s[68][64];
  __shared__ float wsum[4][64], wsq[4][64];

  for (int i = tid; i < 67*64; i += 256) w0s[i>>6][i&63] = W0[i];
  if (tid < 64) w0s[67][tid] = 0.f;

  if (tid < 32){
    int n = g_ball[(size_t)g*KS + tid];
    float4 p = g_p4[b*NPTS + n];
    xt[tid][0] = p.x - g_cx[g];
    xt[tid][1] = p.y - g_cy[g];
    xt[tid][2] = p.z - g_cz[g];
    xt[tid][67] = 0.f;
  }
  {
    int k = tid >> 3, j = tid & 7;
    int n = g_ball[(size_t)g*KS + k];
    const float4* pr = (const float4*)(points + ((size_t)(b*NPTS + n))*64);
    float4 v0 = pr[j*2], v1 = pr[j*2+1];
    int c0 = 3 + j*8;
    xt[k][c0+0]=v0.x; xt[k][c0+1]=v0.y; xt[k][c0+2]=v0.z; xt[k][c0+3]=v0.w;
    xt[k][c0+4]=v1.x; xt[k][c0+5]=v1.y; xt[k][c0+6]=v1.z; xt[k][c0+7]=v1.w;
  }
  __syncthreads();

  const int k0 = (tid >> 4) * 2;
  const int d0 = (tid & 15) * 4;
  const int lane = tid & 63, w = tid >> 6;

  float acc0[4] = {0.f,0.f,0.f,0.f};
  float acc1[4] = {0.f,0.f,0.f,0.f};
#pragma unroll
  for (int cq = 0; cq < 17; ++cq){
    const int c = cq*4;
    float xa[4], xb[4], r0[4], r1[4], r2[4], r3[4];
    *(float4*)xa = *(const float4*)&xt[k0][c];
    *(float4*)xb = *(const float4*)&xt[k0+1][c];
    *(float4*)r0 = *(const float4*)&w0s[c+0][d0];
    *(float4*)r1 = *(const float4*)&w0s[c+1][d0];
    *(float4*)r2 = *(const float4*)&w0s[c+2][d0];
    *(float4*)r3 = *(const float4*)&w0s[c+3][d0];
#pragma unroll
    for (int j=0;j<4;j++){
      acc0[j] = fmaf(xa[0], r0[j], acc0[j]);
      acc0[j] = fmaf(xa[1], r1[j], acc0[j]);
      acc0[j] = fmaf(xa[2], r2[j], acc0[j]);
      acc0[j] = fmaf(xa[3], r3[j], acc0[j]);
      acc1[j] = fmaf(xb[0], r0[j], acc1[j]);
      acc1[j] = fmaf(xb[1], r1[j], acc1[j]);
      acc1[j] = fmaf(xb[2], r2[j], acc1[j]);
      acc1[j] = fmaf(xb[3], r3[j], acc1[j]);
    }
  }
#pragma unroll
  for (int j=0;j<4;j++){ float bv = B0v[d0+j]; acc0[j] += bv; acc1[j] += bv; }

  // store raw Y0
  {
    size_t r0 = ((size_t)g*KS + k0)*64 + d0;
    *(float4*)&g_y0[r0]      = *(float4*)acc0;
    *(float4*)&g_y0[r0 + 64] = *(float4*)acc1;
  }

  float s[4], q[4];
#pragma unroll
  for (int j=0;j<4;j++){ s[j] = acc0[j]+acc1[j]; q[j] = acc0[j]*acc0[j] + acc1[j]*acc1[j]; }
#pragma unroll
  for (int j=0;j<4;j++){
    s[j] += __shfl_down(s[j],32); s[j] += __shfl_down(s[j],16);
    q[j] += __shfl_down(q[j],32); q[j] += __shfl_down(q[j],16);
  }
  if (lane < 16){
#pragma unroll
    for (int j=0;j<4;j++){ wsum[w][lane*4+j] = s[j]; wsq[w][lane*4+j] = q[j]; }
  }
  __syncthreads();
  if (tid < 64){
    float S = wsum[0][tid]+wsum[1][tid]+wsum[2][tid]+wsum[3][tid];
    float Q = wsq[0][tid]+wsq[1][tid]+wsq[2][tid]+wsq[3][tid];
    int bucket = g & 127;
    atomicAdd(&stats[(size_t)bucket*256 + tid], (double)S);
    atomicAdd(&stats[(size_t)bucket*256 + 128 + tid], (double)Q);
  }
}

// ---------------- K_mlpB: Y0 + BN0/ReLU -> L1 -> Y1 (raw) + stats1 ----------------
__global__ __launch_bounds__(256) void k_mlpB(
    const float* __restrict__ W1, const float* __restrict__ B1v){
  double* stats = g_stats + (size_t)1*128*256;
  const int g = blockIdx.x, tid = threadIdx.x;
  __shared__ __align__(16) float xn[32][68];
  __shared__ __align__(16) float w1s[64][64];
  __shared__ float wsum[4][64], wsq[4][64];

  for (int i = tid; i < 64*64; i += 256) w1s[i>>6][i&63] = W1[i];
  {
    int k = tid >> 3, j = tid & 7;
    const float4* pr = (const float4*)(g_y0 + ((size_t)g*KS + k)*64);
    float4 v0 = pr[j*2], v1 = pr[j*2+1];
    int c0 = j*8;
    xn[k][c0+0] = fmaxf(fmaf(v0.x, g_A[c0+0], g_Bv[c0+0]), 0.f);
    xn[k][c0+1] = fmaxf(fmaf(v0.y, g_A[c0+1], g_Bv[c0+1]), 0.f);
    xn[k][c0+2] = fmaxf(fmaf(v0.z, g_A[c0+2], g_Bv[c0+2]), 0.f);
    xn[k][c0+3] = fmaxf(fmaf(v0.w, g_A[c0+3], g_Bv[c0+3]), 0.f);
    xn[k][c0+4] = fmaxf(fmaf(v1.x, g_A[c0+4], g_Bv[c0+4]), 0.f);
    xn[k][c0+5] = fmaxf(fmaf(v1.y, g_A[c0+5], g_Bv[c0+5]), 0.f);
    xn[k][c0+6] = fmaxf(fmaf(v1.z, g_A[c0+6], g_Bv[c0+6]), 0.f);
    xn[k][c0+7] = fmaxf(fmaf(v1.w, g_A[c0+7], g_Bv[c0+7]), 0.f);
  }
  __syncthreads();

  const int k0 = (tid >> 4) * 2;
  const int d0 = (tid & 15) * 4;
  const int lane = tid & 63, w = tid >> 6;

  float bc0[4] = {0.f,0.f,0.f,0.f};
  float bc1[4] = {0.f,0.f,0.f,0.f};
#pragma unroll
  for (int cq = 0; cq < 16; ++cq){
    const int c = cq*4;
    float xa[4], xb[4], r0[4], r1[4], r2[4], r3[4];
    *(float4*)xa = *(const float4*)&xn[k0][c];
    *(float4*)xb = *(const float4*)&xn[k0+1][c];
    *(float4*)r0 = *(const float4*)&w1s[c+0][d0];
    *(float4*)r1 = *(const float4*)&w1s[c+1][d0];
    *(float4*)r2 = *(const float4*)&w1s[c+2][d0];
    *(float4*)r3 = *(const float4*)&w1s[c+3][d0];
#pragma unroll
    for (int j=0;j<4;j++){
      bc0[j] = fmaf(xa[0], r0[j], bc0[j]);
      bc0[j] = fmaf(xa[1], r1[j], bc0[j]);
      bc0[j] = fmaf(xa[2], r2[j], bc0[j]);
      bc0[j] = fmaf(xa[3], r3[j], bc0[j]);
      bc1[j] = fmaf(xb[0], r0[j], bc1[j]);
      bc1[j] = fmaf(xb[1], r1[j], bc1[j]);
      bc1[j] = fmaf(xb[2], r2[j], bc1[j]);
      bc1[j] = fmaf(xb[3], r3[j], bc1[j]);
    }
  }
#pragma unroll
  for (int j=0;j<4;j++){ float bv = B1v[d0+j]; bc0[j] += bv; bc1[j] += bv; }

  {
    size_t r0 = ((size_t)g*KS + k0)*64 + d0;
    *(float4*)&g_y1[r0]      = *(float4*)bc0;
    *(float4*)&g_y1[r0 + 64] = *(float4*)bc1;
  }

  float s[4], q[4];
#pragma unroll
  for (int j=0;j<4;j++){ s[j] = bc0[j]+bc1[j]; q[j] = bc0[j]*bc0[j] + bc1[j]*bc1[j]; }
#pragma unroll
  for (int j=0;j<4;j++){
    s[j] += __shfl_down(s[j],32); s[j] += __shfl_down(s[j],16);
    q[j] += __shfl_down(q[j],32); q[j] += __shfl_down(q[j],16);
  }
  if (lane < 16){
#pragma unroll
    for (int j=0;j<4;j++){ wsum[w][lane*4+j] = s[j]; wsq[w][lane*4+j] = q[j]; }
  }
  __syncthreads();
  if (tid < 64){
    float S = wsum[0][tid]+wsum[1][tid]+wsum[2][tid]+wsum[3][tid];
    float Q = wsq[0][tid]+wsq[1][tid]+wsq[2][tid]+wsq[3][tid];
    int bucket = g & 127;
    atomicAdd(&stats[(size_t)bucket*256 + tid], (double)S);
    atomicAdd(&stats[(size_t)bucket*256 + 128 + tid], (double)Q);
  }
}

// ---------------- K_mlpC: Y1 + BN1/ReLU -> L2 -> stats2 + max/min ----------------
__global__ __launch_bounds__(256) void k_mlpC(
    const float* __restrict__ W2, const float* __restrict__ B2v){
  double* stats = g_stats + (size_t)2*128*256;
  const int g = blockIdx.x, tid = threadIdx.x;
  __shared__ __align__(16) float xt[32][68];
  __shared__ __align__(16) float w2s[64][128];
  __shared__ float wsum[4][128], wsq[4][128];
  __shared__ float wmx[4][128], wmn[4][128];

  for (int i = tid; i < 64*128; i += 256) w2s[i>>7][i&127] = W2[i];
  {
    int k = tid >> 3, j = tid & 7;
    const float4* pr = (const float4*)(g_y1 + ((size_t)g*KS + k)*64);
    float4 v0 = pr[j*2], v1 = pr[j*2+1];
    int c0 = j*8;
    xt[k][c0+0] = fmaxf(fmaf(v0.x, g_A[64+c0+0], g_Bv[64+c0+0]), 0.f);
    xt[k][c0+1] = fmaxf(fmaf(v0.y, g_A[64+c0+1], g_Bv[64+c0+1]), 0.f);
    xt[k][c0+2] = fmaxf(fmaf(v0.z, g_A[64+c0+2], g_Bv[64+c0+2]), 0.f);
    xt[k][c0+3] = fmaxf(fmaf(v0.w, g_A[64+c0+3], g_Bv[64+c0+3]), 0.f);
    xt[k][c0+4] = fmaxf(fmaf(v1.x, g_A[64+c0+4], g_Bv[64+c0+4]), 0.f);
    xt[k][c0+5] = fmaxf(fmaf(v1.y, g_A[64+c0+5], g_Bv[64+c0+5]), 0.f);
    xt[k][c0+6] = fmaxf(fmaf(v1.z, g_A[64+c0+6], g_Bv[64+c0+6]), 0.f);
    xt[k][c0+7] = fmaxf(fmaf(v1.w, g_A[64+c0+7], g_Bv[64+c0+7]), 0.f);
  }
  __syncthreads();

  const int k0 = (tid >> 4) * 2;
  const int e0 = (tid & 15) * 8;
  const int lane = tid & 63, w = tid >> 6;

  float c0a[8] = {0.f,0.f,0.f,0.f,0.f,0.f,0.f,0.f};
  float c1a[8] = {0.f,0.f,0.f,0.f,0.f,0.f,0.f,0.f};
#pragma unroll
  for (int cq = 0; cq < 16; ++cq){
    const int c = cq*4;
    float xa[4], xb[4], r0[8], r1[8], r2[8], r3[8];
    *(float4*)xa = *(const float4*)&xt[k0][c];
    *(float4*)xb = *(const float4*)&xt[k0+1][c];
    *(float4*)&r0[0] = *(const float4*)&w2s[c+0][e0]; *(float4*)&r0[4] = *(const float4*)&w2s[c+0][e0+4];
    *(float4*)&r1[0] = *(const float4*)&w2s[c+1][e0]; *(float4*)&r1[4] = *(const float4*)&w2s[c+1][e0+4];
    *(float4*)&r2[0] = *(const float4*)&w2s[c+2][e0]; *(float4*)&r2[4] = *(const float4*)&w2s[c+2][e0+4];
    *(float4*)&r3[0] = *(const float4*)&w2s[c+3][e0]; *(float4*)&r3[4] = *(const float4*)&w2s[c+3][e0+4];
#pragma unroll
    for (int j=0;j<8;j++){
      c0a[j] = fmaf(xa[0], r0[j], c0a[j]);
      c0a[j] = fmaf(xa[1], r1[j], c0a[j]);
      c0a[j] = fmaf(xa[2], r2[j], c0a[j]);
      c0a[j] = fmaf(xa[3], r3[j], c0a[j]);
      c1a[j] = fmaf(xb[0], r0[j], c1a[j]);
      c1a[j] = fmaf(xb[1], r1[j], c1a[j]);
      c1a[j] = fmaf(xb[2], r2[j], c1a[j]);
      c1a[j] = fmaf(xb[3], r3[j], c1a[j]);
    }
  }
#pragma unroll
  for (int j=0;j<8;j++){ float bv = B2v[e0+j]; c0a[j] += bv; c1a[j] += bv; }

  float s[8], q[8], mx[8], mn[8];
#pragma unroll
  for (int j=0;j<8;j++){
    s[j] = c0a[j]+c1a[j]; q[j] = c0a[j]*c0a[j] + c1a[j]*c1a[j];
    mx[j] = fmaxf(c0a[j], c1a[j]); mn[j] = fminf(c0a[j], c1a[j]);
  }
#pragma unroll
  for (int j=0;j<8;j++){
    s[j] += __shfl_down(s[j],32); s[j] += __shfl_down(s[j],16);
    q[j] += __shfl_down(q[j],32); q[j] += __shfl_down(q[j],16);
    mx[j] = fmaxf(mx[j], __shfl_xor(mx[j],16)); mx[j] = fmaxf(mx[j], __shfl_xor(mx[j],32));
    mn[j] = fminf(mn[j], __shfl_xor(mn[j],16)); mn[j] = fminf(mn[j], __shfl_xor(mn[j],32));
  }
  if (lane < 16){
#pragma unroll
    for (int j=0;j<8;j++){
      wsum[w][lane*8+j] = s[j]; wsq[w][lane*8+j] = q[j];
      wmx[w][lane*8+j] = mx[j]; wmn[w][lane*8+j] = mn[j];
    }
  }
  __syncthreads();
  if (tid < 128){
    float S = wsum[0][tid]+wsum[1][tid]+wsum[2][tid]+wsum[3][tid];
    float Q = wsq[0][tid]+wsq[1][tid]+wsq[2][tid]+wsq[3][tid];
    float MX = fmaxf(fmaxf(wmx[0][tid],wmx[1][tid]), fmaxf(wmx[2][tid],wmx[3][tid]));
    float MN = fminf(fminf(wmn[0][tid],wmn[1][tid]), fminf(wmn[2][tid],wmn[3][tid]));
    g_mmax[(size_t)g*128 + tid] = MX;
    g_mmin[(size_t)g*128 + tid] = MN;
    int bucket = g & 127;
    atomicAdd(&stats[(size_t)bucket*256 + tid], (double)S);
    atomicAdd(&stats[(size_t)bucket*256 + 128 + tid], (double)Q);
  }
}

// ---------------- K_stats ----------------
__global__ void k_stats(int stage, const float* __restrict__ gamma,
                        const float* __restrict__ beta, int aoff, int cout){
  int c = threadIdx.x;
  if (c >= cout) return;
  const double* stats = g_stats + (size_t)stage*128*256;
  double S=0.0, Q=0.0;
  for (int k=0;k<128;k++){ S += stats[(size_t)k*256 + c]; Q += stats[(size_t)k*256 + 128 + c]; }
  const double M = (double)MROWS;
  double mean = S / M;
  double var  = Q / M - mean*mean;
  double inv  = 1.0 / sqrt(var + 1e-5);
  double a    = (double)gamma[c] * inv;
  g_A[aoff+c]  = (float)a;
  g_Bv[aoff+c] = (float)((double)beta[c] - mean * a);
}

// ---------------- K_final ----------------
__global__ __launch_bounds__(256) void k_final(float* __restrict__ outp){
  int idx = blockIdx.x*256 + threadIdx.x;
  int d = idx & 127;
  float a = g_A[128+d], b = g_Bv[128+d];
  float y = (a >= 0.f) ? g_mmax[idx] : g_mmin[idx];
  float v = fmaf(y, a, b);
  outp[idx] = fmaxf(v, 0.f);
}

extern "C" void kernel_launch(void* const* d_in, const int* in_sizes, int n_in,
                              void* d_out, int out_size, void* d_ws, size_t ws_size,
                              hipStream_t stream) {
  (void)in_sizes; (void)n_in; (void)out_size; (void)d_ws; (void)ws_size;
  const float* xyz    = (const float*)d_in[0];
  const float* points = (const float*)d_in[1];
  const int*   start  = (const int*)d_in[2];
  const float* W0 = (const float*)d_in[3];  const float* b0 = (const float*)d_in[4];
  const float* g0 = (const float*)d_in[5];  const float* be0= (const float*)d_in[6];
  const float* W1 = (const float*)d_in[7];  const float* b1 = (const float*)d_in[8];
  const float* g1 = (const float*)d_in[9];  const float* be1= (const float*)d_in[10];
  const float* W2 = (const float*)d_in[11]; const float* b2 = (const float*)d_in[12];
  const float* g2 = (const float*)d_in[13]; const float* be2= (const float*)d_in[14];

  float* out_xyz = (float*)d_out;
  float* out_pts = (float*)d_out + (size_t)NBATCH*SG*3;

  k_zero <<<384, 256, 0, stream>>>();
  k_pre  <<<256, 256, 0, stream>>>(xyz);
  k_fps  <<<NBATCH, NT, 0, stream>>>(start, out_xyz);
  k_ball <<<4096, 256, 0, stream>>>();

  k_mlpA<<<NGRP, 256, 0, stream>>>(points, W0, b0);
  k_stats<<<1, 128, 0, stream>>>(0, g0, be0, 0, 64);
  k_mlpB<<<NGRP, 256, 0, stream>>>(W1, b1);
  k_stats<<<1, 128, 0, stream>>>(1, g1, be1, 64, 64);
  k_mlpC<<<NGRP, 256, 0, stream>>>(W2, b2);
  k_stats<<<1, 128, 0, stream>>>(2, g2, be2, 128, 128);
  k_final<<<8192, 256, 0, stream>>>(out_pts);
}